// Round 6
// baseline (4993.893 us; speedup 1.0000x reference)
//
#include <hip/hip_runtime.h>
#include <stdint.h>

typedef uint16_t u16;
typedef float f32x4 __attribute__((ext_vector_type(4)));

__device__ __forceinline__ float b2f(u16 b){
  union { uint32_t u; float f; } v; v.u = ((uint32_t)b)<<16; return v.f;
}
__device__ __forceinline__ u16 f2b(float f){
  union { float f; uint32_t u; } v; v.f = f;
  return (u16)((v.u + 0x7fffu + ((v.u>>16)&1u))>>16);
}

// ---------------- LoRA t = X @ A^T  (t is [M][8] fp32) ----------------
// grid: (M/4, nmat), block 256. Wave w handles row blockIdx.x*4+w.
// XF32: X is fp32 (raw input x); else bf16 (internal attention output).
template<bool XF32>
__global__ __launch_bounds__(256) void lora_t_kernel(
    const void* __restrict__ Xv,
    const float* __restrict__ A0, const float* __restrict__ A1, const float* __restrict__ A2,
    float* __restrict__ T0, float* __restrict__ T1, float* __restrict__ T2)
{
  const int wid = threadIdx.x>>6, lane = threadIdx.x&63;
  const int m = blockIdx.x*4 + wid;
  const float* A = (blockIdx.y==0)?A0:(blockIdx.y==1)?A1:A2;
  float* T = (blockIdx.y==0)?T0:(blockIdx.y==1)?T1:T2;

  float xf[16];
  if (XF32){
    const float* xp = (const float*)Xv + (size_t)m*1024 + lane*16;
#pragma unroll
    for (int q=0;q<4;q++){
      const f32x4 v = *(const f32x4*)(xp + q*4);
#pragma unroll
      for (int j=0;j<4;j++) xf[q*4+j] = v[j];
    }
  } else {
    const u16* xp = (const u16*)Xv + (size_t)m*1024 + lane*16;
#pragma unroll
    for (int j=0;j<16;j++) xf[j] = b2f(xp[j]);
  }

  float accv[8];
#pragma unroll
  for (int r=0;r<8;r++){
    const float* ap = A + r*1024 + lane*16;
    float s = 0.f;
#pragma unroll
    for (int q=0;q<4;q++){
      const f32x4 av = *(const f32x4*)(ap + q*4);
#pragma unroll
      for (int j=0;j<4;j++) s += xf[q*4+j]*av[j];
    }
    accv[r] = s;
  }
#pragma unroll
  for (int r=0;r<8;r++){
    float s = accv[r];
    s += __shfl_xor(s,1);  s += __shfl_xor(s,2);  s += __shfl_xor(s,4);
    s += __shfl_xor(s,8);  s += __shfl_xor(s,16); s += __shfl_xor(s,32);
    accv[r] = s;
  }
  if (lane==0){
#pragma unroll
    for (int r=0;r<8;r++) T[(size_t)m*8 + r] = accv[r];
  }
}

// ---------------- VALU GEMM: Out = X @ W^T + bias + 2*T@Bl^T ----------------
// X: [4096][1024] fp32 (XF32) or bf16. W: [1024][1024] fp32. Out: bf16 (internal)
// or fp32 (outf32=1, final d_out). block 256 (16x16), tile 64x64, K-step 32,
// 4x4 per thread. grid (16,64).
template<bool XF32>
__global__ __launch_bounds__(256) void gemm_lora_kernel(
    const void* __restrict__ Xv, const float* __restrict__ W,
    const float* __restrict__ bias, const float* __restrict__ T,
    const float* __restrict__ Bl, void* __restrict__ Out, int outf32)
{
  __shared__ float Xs[32*68];   // Xs[k][m]  (stride 68 floats)
  __shared__ float Ws[32*68];   // Ws[k][n]
  const int tid = threadIdx.x;
  const int ty = tid>>4, tx = tid&15;
  const int m0 = blockIdx.y*64, n0 = blockIdx.x*64;

  float acc[4][4];
#pragma unroll
  for (int i=0;i<4;i++)
#pragma unroll
    for (int j=0;j<4;j++) acc[i][j] = 0.f;

  for (int k0=0;k0<1024;k0+=32){
#pragma unroll
    for (int i=0;i<8;i++){
      const int idx = i*256 + tid;        // 0..2047
      const int row = idx>>5, col = idx&31;
      float xv;
      if (XF32) xv = ((const float*)Xv)[(size_t)(m0+row)*1024 + k0 + col];
      else      xv = b2f(((const u16*)Xv)[(size_t)(m0+row)*1024 + k0 + col]);
      Xs[col*68 + row] = xv;
      Ws[col*68 + row] = W[(size_t)(n0+row)*1024 + k0 + col];
    }
    __syncthreads();
#pragma unroll 8
    for (int kk=0;kk<32;kk++){
      const f32x4 a = *(const f32x4*)(Xs + kk*68 + ty*4);
      const f32x4 b = *(const f32x4*)(Ws + kk*68 + tx*4);
#pragma unroll
      for (int i=0;i<4;i++)
#pragma unroll
        for (int j=0;j<4;j++) acc[i][j] += a[i]*b[j];
    }
    __syncthreads();
  }

  // epilogue: + bias[n] + 2 * t[m]·Bl[n]
#pragma unroll
  for (int i=0;i<4;i++){
    const int mb = m0 + ty*4 + i;
    float tr[8];
#pragma unroll
    for (int r=0;r<8;r++) tr[r] = T[(size_t)mb*8 + r];
#pragma unroll
    for (int j=0;j<4;j++){
      const int n = n0 + tx*4 + j;
      float dot = 0.f;
#pragma unroll
      for (int r=0;r<8;r++) dot += tr[r]*Bl[(size_t)n*8 + r];
      const float v = acc[i][j] + bias[n] + 2.0f*dot;
      if (outf32) ((float*)Out)[(size_t)mb*1024 + n] = v;
      else        ((u16*)Out)[(size_t)mb*1024 + n]   = f2b(v);
    }
  }
}

// ---------------- VALU flash attention ----------------
// block 256 = 4 waves; wave w = query blockIdx.x*4+w, head blockIdx.y, batch z.
// Q,K,V: [n][s][1024] bf16 natural layout. Out: same. grid (512,16,2).
__global__ __launch_bounds__(256) void attn_kernel(
    const u16* __restrict__ Q, const u16* __restrict__ K,
    const u16* __restrict__ V, u16* __restrict__ Out)
{
  __shared__ float Ks[64*65];   // Ks[key][d]
  __shared__ float Vs[64*65];   // Vs[d][key]  (transposed at staging)
  const int tid = threadIdx.x, wid = tid>>6, lane = tid&63;
  const int q = blockIdx.x*4 + wid;
  const int h = blockIdx.y, nb = blockIdx.z;
  const size_t base = (size_t)(nb*2048)*1024 + h*64;   // + s*1024 + d

  const float qd = b2f(Q[base + (size_t)q*1024 + lane]);   // lane = d
  float m = -3.0e38f, l = 0.f, o = 0.f;                     // o accumulates dim d=lane

  for (int kt=0; kt<2048; kt+=64){
#pragma unroll
    for (int i=0;i<16;i++){
      const int idx = i*256 + tid;      // 0..4095
      const int kr = idx>>6, kc = idx&63;
      Ks[kr*65 + kc] = b2f(K[base + (size_t)(kt+kr)*1024 + kc]);
      Vs[kc*65 + kr] = b2f(V[base + (size_t)(kt+kr)*1024 + kc]);
    }
    __syncthreads();

    // s for key kt+lane : dot(q, K[key]) / 8
    float s = 0.f;
#pragma unroll 8
    for (int d=0; d<64; d++)
      s += __shfl(qd, d) * Ks[lane*65 + d];
    s *= 0.125f;

    // online softmax across the 64 keys of this tile (all 64 lanes)
    float mx = s;
    mx = fmaxf(mx, __shfl_xor(mx,1));  mx = fmaxf(mx, __shfl_xor(mx,2));
    mx = fmaxf(mx, __shfl_xor(mx,4));  mx = fmaxf(mx, __shfl_xor(mx,8));
    mx = fmaxf(mx, __shfl_xor(mx,16)); mx = fmaxf(mx, __shfl_xor(mx,32));
    const float mnew  = fmaxf(m, mx);
    const float alpha = __expf(m - mnew);
    const float p = __expf(s - mnew);          // lane's key weight
    float sum = p;
    sum += __shfl_xor(sum,1);  sum += __shfl_xor(sum,2);
    sum += __shfl_xor(sum,4);  sum += __shfl_xor(sum,8);
    sum += __shfl_xor(sum,16); sum += __shfl_xor(sum,32);
    l = l*alpha + sum;
    m = mnew;
    o *= alpha;

    // o[d=lane] += sum_key p_key * V[key][d]
#pragma unroll 8
    for (int kk=0; kk<64; kk++)
      o += __shfl(p, kk) * Vs[lane*65 + kk];

    __syncthreads();
  }

  Out[base + (size_t)q*1024 + lane] = f2b(o / l);
}

extern "C" void kernel_launch(void* const* d_in, const int* in_sizes, int n_in,
                              void* d_out, int out_size, void* d_ws, size_t ws_size,
                              hipStream_t stream)
{
  const float* x  = (const float*)d_in[0];
  const float* Wq = (const float*)d_in[1];  const float* bq = (const float*)d_in[2];
  const float* Aq = (const float*)d_in[3];  const float* Bq = (const float*)d_in[4];
  const float* Wk = (const float*)d_in[5];  const float* bk = (const float*)d_in[6];
  const float* Ak = (const float*)d_in[7];  const float* Bk = (const float*)d_in[8];
  const float* Wv = (const float*)d_in[9];  const float* bv = (const float*)d_in[10];
  const float* Av = (const float*)d_in[11]; const float* Bv = (const float*)d_in[12];
  const float* Wo = (const float*)d_in[13]; const float* bo = (const float*)d_in[14];
  const float* Ao = (const float*)d_in[15]; const float* Bo = (const float*)d_in[16];

  char* ws = (char*)d_ws;
  float* tq = (float*)(ws + 0);
  float* tk = (float*)(ws + 131072);
  float* tv = (float*)(ws + 262144);
  float* to = (float*)(ws + 393216);
  u16* Qb = (u16*)(ws + 524288);
  u16* Kb = (u16*)(ws + 524288 + 8388608);
  u16* Vb = (u16*)(ws + 524288 + 2*8388608);
  u16* Ab = (u16*)(ws + 524288 + 3*8388608);

  lora_t_kernel<true><<<dim3(1024,3),256,0,stream>>>(x, Aq, Ak, Av, tq, tk, tv);
  gemm_lora_kernel<true><<<dim3(16,64),256,0,stream>>>(x, Wq, bq, tq, Bq, Qb, 0);
  gemm_lora_kernel<true><<<dim3(16,64),256,0,stream>>>(x, Wk, bk, tk, Bk, Kb, 0);
  gemm_lora_kernel<true><<<dim3(16,64),256,0,stream>>>(x, Wv, bv, tv, Bv, Vb, 0);
  attn_kernel<<<dim3(512,16,2),256,0,stream>>>(Qb, Kb, Vb, Ab);
  lora_t_kernel<false><<<dim3(1024,1),256,0,stream>>>(Ab, Ao, Ao, Ao, to, to, to);
  gemm_lora_kernel<false><<<dim3(16,64),256,0,stream>>>(Ab, Wo, bo, to, Bo, d_out, 1);
}

// Round 7
// 402.625 us; speedup vs baseline: 12.4033x; 12.4033x over previous
//
#include <hip/hip_runtime.h>
#include <stdint.h>

typedef uint16_t u16;
typedef short s16x8 __attribute__((ext_vector_type(8)));
typedef float f32x4 __attribute__((ext_vector_type(4)));
typedef unsigned short u16x4 __attribute__((ext_vector_type(4)));

#define MFMA16(a,b,c) __builtin_amdgcn_mfma_f32_16x16x32_bf16((a),(b),(c),0,0,0)

__device__ __forceinline__ float b2f(u16 b){
  union { uint32_t u; float f; } v; v.u = ((uint32_t)b)<<16; return v.f;
}
__device__ __forceinline__ u16 f2b(float f){
  union { float f; uint32_t u; } v; v.f = f;
  return (u16)((v.u + 0x7fffu + ((v.u>>16)&1u))>>16);
}

// ---------------- LoRA t = X @ A^T  (t is [M][8] fp32) ----------------
// grid: (M/4, nmat), block 256. Wave w handles row blockIdx.x*4+w.
template<bool XF32>
__global__ __launch_bounds__(256) void lora_t_kernel(
    const void* __restrict__ Xv,
    const float* __restrict__ A0, const float* __restrict__ A1, const float* __restrict__ A2,
    float* __restrict__ T0, float* __restrict__ T1, float* __restrict__ T2)
{
  const int wid = threadIdx.x>>6, lane = threadIdx.x&63;
  const int m = blockIdx.x*4 + wid;
  const float* A = (blockIdx.y==0)?A0:(blockIdx.y==1)?A1:A2;
  float* T = (blockIdx.y==0)?T0:(blockIdx.y==1)?T1:T2;

  float xf[16];
  if (XF32){
    const float* xp = (const float*)Xv + (size_t)m*1024 + lane*16;
#pragma unroll
    for (int q=0;q<4;q++){
      const f32x4 v = *(const f32x4*)(xp + q*4);
#pragma unroll
      for (int j=0;j<4;j++) xf[q*4+j] = v[j];
    }
  } else {
    const u16* xp = (const u16*)Xv + (size_t)m*1024 + lane*16;
#pragma unroll
    for (int j=0;j<16;j++) xf[j] = b2f(xp[j]);
  }

  float accv[8];
#pragma unroll
  for (int r=0;r<8;r++){
    const float* ap = A + r*1024 + lane*16;
    float s = 0.f;
#pragma unroll
    for (int q=0;q<4;q++){
      const f32x4 av = *(const f32x4*)(ap + q*4);
#pragma unroll
      for (int j=0;j<4;j++) s += xf[q*4+j]*av[j];
    }
    accv[r] = s;
  }
#pragma unroll
  for (int r=0;r<8;r++){
    float s = accv[r];
    s += __shfl_xor(s,1);  s += __shfl_xor(s,2);  s += __shfl_xor(s,4);
    s += __shfl_xor(s,8);  s += __shfl_xor(s,16); s += __shfl_xor(s,32);
    accv[r] = s;
  }
  if (lane==0){
#pragma unroll
    for (int r=0;r<8;r++) T[(size_t)m*8 + r] = accv[r];
  }
}

// ---------------- MFMA GEMM: Out = X @ W^T + bias + 2*T@Bl^T ----------------
// X: [4096][1024] fp32 (XF32) or bf16; W: [1024][1024] fp32 -> bf16 in staging.
// mode 0: Out[m][n] bf16.  mode 1 (V): Out[(b*16+h)*64+d][s] bf16 transposed.
// mode 2: Out[m][n] fp32 (final output).
// grid (8,32), block 256 (4 waves, 2x2), padded LDS stride 40.
template<bool XF32>
__global__ __launch_bounds__(256,2) void gemm_lora_kernel(
    const void* __restrict__ Xv, const float* __restrict__ W,
    const float* __restrict__ bias, const float* __restrict__ T,
    const float* __restrict__ Bl, void* __restrict__ Out, int mode)
{
  __shared__ u16 At[128*40];
  __shared__ u16 Bt[128*40];
  const int tid = threadIdx.x;
  const int wid = tid>>6, lane = tid&63;
  const int quad = lane>>4, l16 = lane&15;
  const int wm = wid>>1, wn = wid&1;
  const int m0 = blockIdx.y<<7, n0 = blockIdx.x<<7;

  f32x4 acc[4][4];
#pragma unroll
  for (int i=0;i<4;i++)
#pragma unroll
    for (int j=0;j<4;j++) acc[i][j] = f32x4{0.f,0.f,0.f,0.f};

  for (int k0=0;k0<1024;k0+=32){
#pragma unroll
    for (int p=0;p<2;p++){
      const int s = p*256 + tid;          // chunk id, 0..511 (8 elems each)
      const int row = s>>2, c = s&3;
      s16x8 va;
      if (XF32){
        const float* xp = (const float*)Xv + (size_t)(m0+row)*1024 + k0 + c*8;
        const f32x4 a0 = *(const f32x4*)(xp);
        const f32x4 a1 = *(const f32x4*)(xp+4);
#pragma unroll
        for (int j=0;j<4;j++){ va[j] = (short)f2b(a0[j]); va[4+j] = (short)f2b(a1[j]); }
      } else {
        va = *(const s16x8*)((const u16*)Xv + (size_t)(m0+row)*1024 + k0 + c*8);
      }
      *(s16x8*)(At + row*40 + c*8) = va;
      const float* wp = W + (size_t)(n0+row)*1024 + k0 + c*8;
      const f32x4 b0 = *(const f32x4*)(wp);
      const f32x4 b1 = *(const f32x4*)(wp+4);
      s16x8 vb;
#pragma unroll
      for (int j=0;j<4;j++){ vb[j] = (short)f2b(b0[j]); vb[4+j] = (short)f2b(b1[j]); }
      *(s16x8*)(Bt + row*40 + c*8) = vb;
    }
    __syncthreads();
    s16x8 af[4], bfr[4];
#pragma unroll
    for (int t=0;t<4;t++){
      const int r = wm*64 + t*16 + l16;
      af[t]  = *(const s16x8*)(At + r*40 + quad*8);
      const int c = wn*64 + t*16 + l16;
      bfr[t] = *(const s16x8*)(Bt + c*40 + quad*8);
    }
#pragma unroll
    for (int tm=0;tm<4;tm++)
#pragma unroll
      for (int tn=0;tn<4;tn++)
        acc[tm][tn] = MFMA16(af[tm], bfr[tn], acc[tm][tn]);
    __syncthreads();
  }

  // Epilogue: bias + 2.0 * t[m]·Bl[n]
#pragma unroll
  for (int tn=0;tn<4;tn++){
    const int n = n0 + wn*64 + tn*16 + l16;
    float bl[8];
#pragma unroll
    for (int r=0;r<8;r++) bl[r] = Bl[(size_t)n*8 + r];
    const float bn = bias[n];
#pragma unroll
    for (int tm=0;tm<4;tm++){
      const int mb = m0 + wm*64 + tm*16 + quad*4;
      float v[4];
#pragma unroll
      for (int rg=0;rg<4;rg++){
        const float* tp = T + (size_t)(mb+rg)*8;
        float dot = 0.f;
#pragma unroll
        for (int r=0;r<8;r++) dot += tp[r]*bl[r];
        v[rg] = acc[tm][tn][rg] + bn + 2.0f*dot;
      }
      if (mode==0){
#pragma unroll
        for (int rg=0;rg<4;rg++)
          ((u16*)Out)[(size_t)(mb+rg)*1024 + n] = f2b(v[rg]);
      } else if (mode==2){
#pragma unroll
        for (int rg=0;rg<4;rg++)
          ((float*)Out)[(size_t)(mb+rg)*1024 + n] = v[rg];
      } else {
        const int batch = mb>>11, sI = mb&2047;
        const int hh = n>>6, dd = n&63;
        u16x4 pk;
#pragma unroll
        for (int rg=0;rg<4;rg++) pk[rg] = f2b(v[rg]);
        *(u16x4*)((u16*)Out + (size_t)((batch*16+hh)*64+dd)*2048 + sI) = pk;
      }
    }
  }
}

// ---------------- MFMA flash attention ----------------
// grid (S/128=16, H=16, N=2), block 256 (4 waves, 32 q-rows each)
// Q,K: [n][s][1024] bf16 ; Vt: [(n*16+h)*64+d][s] bf16 ; Out: [n][s][1024] bf16
// Padded tiles: K [128][72], Vt [64][136], P [128][136]. ~69 KB LDS.
__global__ __launch_bounds__(256,2) void attn_kernel(
    const u16* __restrict__ Q, const u16* __restrict__ K,
    const u16* __restrict__ Vt, u16* __restrict__ Out)
{
  __shared__ u16 Kt[128*72];
  __shared__ u16 Vtl[64*136];
  __shared__ u16 Pt[128*136];
  const int tid = threadIdx.x;
  const int wid = tid>>6, lane = tid&63;
  const int quad = lane>>4, l16 = lane&15;
  const int q0 = blockIdx.x<<7;
  const int h = blockIdx.y, nb = blockIdx.z;

  s16x8 qf[2][2];
#pragma unroll
  for (int tm=0;tm<2;tm++){
    const int row = q0 + wid*32 + tm*16 + l16;
#pragma unroll
    for (int dh=0;dh<2;dh++)
      qf[tm][dh] = *(const s16x8*)(Q + (size_t)(nb*2048+row)*1024 + h*64 + dh*32 + quad*8);
  }
  f32x4 O[2][4];
  float mr[2][4], lr[2][4];
#pragma unroll
  for (int tm=0;tm<2;tm++){
#pragma unroll
    for (int td=0;td<4;td++) O[tm][td] = f32x4{0.f,0.f,0.f,0.f};
#pragma unroll
    for (int rg=0;rg<4;rg++){ mr[tm][rg] = -3.0e38f; lr[tm][rg] = 0.f; }
  }

  for (int kt=0; kt<2048; kt+=128){
#pragma unroll
    for (int p=0;p<4;p++){
      const int s = p*256 + tid;          // 16B slot id, 0..1023
      { const int row = s>>3, c = s&7;
        const s16x8 v = *(const s16x8*)(K + (size_t)(nb*2048+kt+row)*1024 + h*64 + c*8);
        *(s16x8*)(Kt + row*72 + c*8) = v; }
      { const int row = s>>4, c = s&15;
        const s16x8 v = *(const s16x8*)(Vt + (size_t)((nb*16+h)*64+row)*2048 + kt + c*8);
        *(s16x8*)(Vtl + row*136 + c*8) = v; }
    }
    __syncthreads();

    // S = (Q K^T) / 8
    f32x4 S[2][8];
#pragma unroll
    for (int tn=0;tn<8;tn++){
      const int key = tn*16 + l16;
      const s16x8 kf0 = *(const s16x8*)(Kt + key*72 + quad*8);
      const s16x8 kf1 = *(const s16x8*)(Kt + key*72 + 32 + quad*8);
#pragma unroll
      for (int tm=0;tm<2;tm++){
        f32x4 z = f32x4{0.f,0.f,0.f,0.f};
        z = MFMA16(qf[tm][0], kf0, z);
        z = MFMA16(qf[tm][1], kf1, z);
        S[tm][tn] = z * 0.125f;
      }
    }

    // online softmax (row stats live in 16 lanes of each quad-group)
#pragma unroll
    for (int tm=0;tm<2;tm++)
#pragma unroll
      for (int rg=0;rg<4;rg++){
        float mx = S[tm][0][rg];
#pragma unroll
        for (int tn=1;tn<8;tn++) mx = fmaxf(mx, S[tm][tn][rg]);
        mx = fmaxf(mx, __shfl_xor(mx,1));
        mx = fmaxf(mx, __shfl_xor(mx,2));
        mx = fmaxf(mx, __shfl_xor(mx,4));
        mx = fmaxf(mx, __shfl_xor(mx,8));
        const float mnew  = fmaxf(mr[tm][rg], mx);
        const float alpha = __expf(mr[tm][rg] - mnew);
        float sum = 0.f;
#pragma unroll
        for (int tn=0;tn<8;tn++){
          const float pv = __expf(S[tm][tn][rg] - mnew);
          S[tm][tn][rg] = pv;          // reuse S as P
          sum += pv;
        }
        sum += __shfl_xor(sum,1);
        sum += __shfl_xor(sum,2);
        sum += __shfl_xor(sum,4);
        sum += __shfl_xor(sum,8);
        lr[tm][rg] = lr[tm][rg]*alpha + sum;
        mr[tm][rg] = mnew;
#pragma unroll
        for (int td=0;td<4;td++) O[tm][td][rg] *= alpha;
      }

    // P: C-layout regs -> LDS [q][key]
#pragma unroll
    for (int tm=0;tm<2;tm++){
      const int qrow = wid*32 + tm*16 + quad*4;
#pragma unroll
      for (int rg=0;rg<4;rg++)
#pragma unroll
        for (int tn=0;tn<8;tn++)
          Pt[(qrow+rg)*136 + tn*16 + l16] = f2b(S[tm][tn][rg]);
    }

    // O += P V  (P reads are intra-wave: same 32 rows this wave just wrote)
#pragma unroll
    for (int kb=0;kb<4;kb++){
      s16x8 pf[2];
#pragma unroll
      for (int tm=0;tm<2;tm++)
        pf[tm] = *(const s16x8*)(Pt + (wid*32+tm*16+l16)*136 + kb*32 + quad*8);
#pragma unroll
      for (int td=0;td<4;td++){
        const int dd = td*16 + l16;
        const s16x8 vf = *(const s16x8*)(Vtl + dd*136 + kb*32 + quad*8);
#pragma unroll
        for (int tm=0;tm<2;tm++)
          O[tm][td] = MFMA16(pf[tm], vf, O[tm][td]);
      }
    }
    __syncthreads();   // all reads done before next tile's staging overwrites
  }

  // epilogue: O/l -> bf16
#pragma unroll
  for (int tm=0;tm<2;tm++)
#pragma unroll
    for (int rg=0;rg<4;rg++){
      const float inv = 1.0f / lr[tm][rg];
      const int q = q0 + wid*32 + tm*16 + quad*4 + rg;
#pragma unroll
      for (int td=0;td<4;td++)
        Out[(size_t)(nb*2048+q)*1024 + h*64 + td*16 + l16] = f2b(O[tm][td][rg]*inv);
    }
}

extern "C" void kernel_launch(void* const* d_in, const int* in_sizes, int n_in,
                              void* d_out, int out_size, void* d_ws, size_t ws_size,
                              hipStream_t stream)
{
  const float* x  = (const float*)d_in[0];
  const float* Wq = (const float*)d_in[1];  const float* bq = (const float*)d_in[2];
  const float* Aq = (const float*)d_in[3];  const float* Bq = (const float*)d_in[4];
  const float* Wk = (const float*)d_in[5];  const float* bk = (const float*)d_in[6];
  const float* Ak = (const float*)d_in[7];  const float* Bk = (const float*)d_in[8];
  const float* Wv = (const float*)d_in[9];  const float* bv = (const float*)d_in[10];
  const float* Av = (const float*)d_in[11]; const float* Bv = (const float*)d_in[12];
  const float* Wo = (const float*)d_in[13]; const float* bo = (const float*)d_in[14];
  const float* Ao = (const float*)d_in[15]; const float* Bo = (const float*)d_in[16];

  char* ws = (char*)d_ws;
  float* tq = (float*)(ws + 0);
  float* tk = (float*)(ws + 131072);
  float* tv = (float*)(ws + 262144);
  float* to = (float*)(ws + 393216);
  u16* Qb  = (u16*)(ws + 524288);
  u16* Kb  = (u16*)(ws + 524288 + 8388608);
  u16* Vtb = (u16*)(ws + 524288 + 2*8388608);
  u16* Ab  = (u16*)(ws + 524288 + 3*8388608);

  lora_t_kernel<true><<<dim3(1024,3),256,0,stream>>>(x, Aq, Ak, Av, tq, tk, tv);
  gemm_lora_kernel<true><<<dim3(8,32),256,0,stream>>>(x, Wq, bq, tq, Bq, Qb, 0);
  gemm_lora_kernel<true><<<dim3(8,32),256,0,stream>>>(x, Wk, bk, tk, Bk, Kb, 0);
  gemm_lora_kernel<true><<<dim3(8,32),256,0,stream>>>(x, Wv, bv, tv, Bv, Vtb, 1);
  attn_kernel<<<dim3(16,16,2),256,0,stream>>>(Qb, Kb, Vtb, Ab);
  lora_t_kernel<false><<<dim3(1024,1),256,0,stream>>>(Ab, Ao, Ao, Ao, to, to, to);
  gemm_lora_kernel<false><<<dim3(8,32),256,0,stream>>>(Ab, Wo, bo, to, Bo, d_out, 2);
}